// Round 1
// baseline (63654.755 us; speedup 1.0000x reference)
//
#include <hip/hip_runtime.h>
#include <math.h>

// LSTM: B=32, T=512, D=1024, H=1024. fp32 baseline.
// Inputs: X[32][512][1024], Wa_x..Wo_x [1024][1024], Wa_h..Wo_h [1024][1024], ba..bo [1024]
// Output: h [32][512][1024] fp32.

__device__ __forceinline__ float sigm_f(float x) {
    return 1.0f / (1.0f + __expf(-x));
}
__device__ __forceinline__ float tanh_f(float x) {
    // 1 - 2/(e^{2x}+1): saturates cleanly to +-1 without NaN at large |x|
    return 1.0f - 2.0f / (__expf(2.0f * x) + 1.0f);
}

// ---------------- Projection GEMM ----------------
// xg[t][b][g*1024+c] = sum_d X[b][t][d] * Wx_g[d][c]     (bias added later)
// M = 16384 (r = b*512+t), K = 1024, N = 4096. Tile 64x64, 256 thr, 4x4 micro.
__global__ __launch_bounds__(256)
void proj_kernel(const float* __restrict__ X,
                 const float* __restrict__ Wa,
                 const float* __restrict__ Wi,
                 const float* __restrict__ Wf,
                 const float* __restrict__ Wo,
                 float* __restrict__ xg)
{
    __shared__ float As[64][36];   // padded stride 36 (16B-aligned rows, conflict-light)
    __shared__ float Bs[32][64];

    const int bx = blockIdx.x & 63;        // N tile (64 tiles of 64 cols)
    const int by = blockIdx.x >> 6;        // M tile (256 tiles of 64 rows)
    const int tid = threadIdx.x;
    const int tx = tid & 15, ty = tid >> 4;

    const int col0 = bx * 64;
    const int gate = col0 >> 10;           // 64 | 1024 -> tile within one gate
    const float* Wg = (gate == 0) ? Wa : ((gate == 1) ? Wi : ((gate == 2) ? Wf : Wo));
    const int wcol0 = col0 & 1023;
    const int row0 = by * 64;

    float acc[4][4];
#pragma unroll
    for (int i = 0; i < 4; i++)
#pragma unroll
        for (int j = 0; j < 4; j++) acc[i][j] = 0.f;

    for (int kt = 0; kt < 1024; kt += 32) {
#pragma unroll
        for (int u = 0; u < 2; u++) {
            int f4 = u * 256 + tid;
            int r  = f4 >> 3;
            int kq = (f4 & 7) << 2;
            float4 v = *reinterpret_cast<const float4*>(X + (size_t)(row0 + r) * 1024 + kt + kq);
            *reinterpret_cast<float4*>(&As[r][kq]) = v;
        }
#pragma unroll
        for (int u = 0; u < 2; u++) {
            int f4 = u * 256 + tid;
            int c4 = (f4 & 15) << 2;
            int kk = f4 >> 4;
            float4 v = *reinterpret_cast<const float4*>(Wg + (size_t)(kt + kk) * 1024 + wcol0 + c4);
            *reinterpret_cast<float4*>(&Bs[kk][c4]) = v;
        }
        __syncthreads();
#pragma unroll
        for (int kk = 0; kk < 32; kk++) {
            float a0 = As[ty * 4 + 0][kk];
            float a1 = As[ty * 4 + 1][kk];
            float a2 = As[ty * 4 + 2][kk];
            float a3 = As[ty * 4 + 3][kk];
            float4 b = *reinterpret_cast<const float4*>(&Bs[kk][tx * 4]);
            acc[0][0] += a0 * b.x; acc[0][1] += a0 * b.y; acc[0][2] += a0 * b.z; acc[0][3] += a0 * b.w;
            acc[1][0] += a1 * b.x; acc[1][1] += a1 * b.y; acc[1][2] += a1 * b.z; acc[1][3] += a1 * b.w;
            acc[2][0] += a2 * b.x; acc[2][1] += a2 * b.y; acc[2][2] += a2 * b.z; acc[2][3] += a2 * b.w;
            acc[3][0] += a3 * b.x; acc[3][1] += a3 * b.y; acc[3][2] += a3 * b.z; acc[3][3] += a3 * b.w;
        }
        __syncthreads();
    }
#pragma unroll
    for (int i = 0; i < 4; i++) {
        int r = row0 + ty * 4 + i;
        int b = r >> 9, t = r & 511;
        float4 v = make_float4(acc[i][0], acc[i][1], acc[i][2], acc[i][3]);
        *reinterpret_cast<float4*>(xg + ((size_t)t * 32 + b) * 4096 + col0 + tx * 4) = v;
    }
}

// ---------------- Recurrent step ----------------
// One kernel per timestep. 256 blocks; block bx owns h-columns [bx*4, bx*4+4).
// GEMM phase: 256 threads = 2 K-halves x (32 rows x 4 gates); each thread computes
// a float4 of g (4 h-cols of one gate, one row, one K half). h staged fully in LDS.
// Partials exchanged via small LDS g-buffer, then 128 threads do the gate math.
template<bool FIRST, bool FUSED>
__global__ __launch_bounds__(256)
void step_kernel(const float* __restrict__ hprev,   // [32][1024]
                 float* __restrict__ hnext,         // [32][1024]
                 float* __restrict__ sbuf,          // [32][1024] (in-place)
                 const float* __restrict__ xg,      // [512][32][4096] (unused if FUSED)
                 const float* __restrict__ X,       // [32][512][1024] (used if FUSED)
                 const float* __restrict__ Wah, const float* __restrict__ Wih,
                 const float* __restrict__ Wfh, const float* __restrict__ Woh,
                 const float* __restrict__ Wax, const float* __restrict__ Wix,
                 const float* __restrict__ Wfx, const float* __restrict__ Wox,
                 const float* __restrict__ ba, const float* __restrict__ bi,
                 const float* __restrict__ bfv, const float* __restrict__ bo,
                 float* __restrict__ out, int t)
{
    __shared__ float hs[32 * 1028];        // padded stride 1028 -> conflict-free strided reads
    __shared__ float gs[2][32][16];        // [khalf][row][gate*4+hc]

    const int tid  = threadIdx.x;
    const int hc0  = blockIdx.x * 4;

    const int kh   = tid >> 7;             // K half: 0/1
    const int gtid = tid & 127;
    const int r    = gtid >> 2;            // 0..31
    const int gate = gtid & 3;             // 0..3 (a,i,f,o)
    const int k0   = kh * 512;

    float4 acc = make_float4(0.f, 0.f, 0.f, 0.f);

    if (!FIRST) {
        // stage h_prev (32x1024) into LDS
        for (int u = 0; u < 32; u++) {
            int f4 = u * 256 + tid;
            int rr = f4 >> 8;
            int kq = (f4 & 255) << 2;
            float4 v = *reinterpret_cast<const float4*>(hprev + rr * 1024 + kq);
            *reinterpret_cast<float4*>(&hs[rr * 1028 + kq]) = v;
        }
        __syncthreads();
        const float* Wg = (gate == 0) ? Wah : ((gate == 1) ? Wih : ((gate == 2) ? Wfh : Woh));
        const float* Wp = Wg + hc0;
#pragma unroll 4
        for (int k = k0; k < k0 + 512; k += 4) {
            float4 hv = *reinterpret_cast<const float4*>(&hs[r * 1028 + k]);
            float4 w0 = *reinterpret_cast<const float4*>(Wp + (size_t)(k + 0) * 1024);
            float4 w1 = *reinterpret_cast<const float4*>(Wp + (size_t)(k + 1) * 1024);
            float4 w2 = *reinterpret_cast<const float4*>(Wp + (size_t)(k + 2) * 1024);
            float4 w3 = *reinterpret_cast<const float4*>(Wp + (size_t)(k + 3) * 1024);
            acc.x += hv.x * w0.x + hv.y * w1.x + hv.z * w2.x + hv.w * w3.x;
            acc.y += hv.x * w0.y + hv.y * w1.y + hv.z * w2.y + hv.w * w3.y;
            acc.z += hv.x * w0.z + hv.y * w1.z + hv.z * w2.z + hv.w * w3.z;
            acc.w += hv.x * w0.w + hv.y * w1.w + hv.z * w2.w + hv.w * w3.w;
        }
    }

    if (FUSED) {
        // phase 2: x_t @ Wx, reusing the same LDS buffer for x_t
        __syncthreads();
        for (int u = 0; u < 32; u++) {
            int f4 = u * 256 + tid;
            int rr = f4 >> 8;
            int kq = (f4 & 255) << 2;
            float4 v = *reinterpret_cast<const float4*>(X + ((size_t)rr * 512 + t) * 1024 + kq);
            *reinterpret_cast<float4*>(&hs[rr * 1028 + kq]) = v;
        }
        __syncthreads();
        const float* Wg = (gate == 0) ? Wax : ((gate == 1) ? Wix : ((gate == 2) ? Wfx : Wox));
        const float* Wp = Wg + hc0;
#pragma unroll 4
        for (int k = k0; k < k0 + 512; k += 4) {
            float4 hv = *reinterpret_cast<const float4*>(&hs[r * 1028 + k]);
            float4 w0 = *reinterpret_cast<const float4*>(Wp + (size_t)(k + 0) * 1024);
            float4 w1 = *reinterpret_cast<const float4*>(Wp + (size_t)(k + 1) * 1024);
            float4 w2 = *reinterpret_cast<const float4*>(Wp + (size_t)(k + 2) * 1024);
            float4 w3 = *reinterpret_cast<const float4*>(Wp + (size_t)(k + 3) * 1024);
            acc.x += hv.x * w0.x + hv.y * w1.x + hv.z * w2.x + hv.w * w3.x;
            acc.y += hv.x * w0.y + hv.y * w1.y + hv.z * w2.y + hv.w * w3.y;
            acc.z += hv.x * w0.z + hv.y * w1.z + hv.z * w2.z + hv.w * w3.z;
            acc.w += hv.x * w0.w + hv.y * w1.w + hv.z * w2.w + hv.w * w3.w;
        }
    }

    *reinterpret_cast<float4*>(&gs[kh][r][gate * 4]) = acc;
    __syncthreads();

    if (tid < 128) {
        const int rr = tid >> 2;
        const int hc = tid & 3;
        const int h  = hc0 + hc;

        float ga = gs[0][rr][0 * 4 + hc] + gs[1][rr][0 * 4 + hc] + ba[h];
        float gi = gs[0][rr][1 * 4 + hc] + gs[1][rr][1 * 4 + hc] + bi[h];
        float gf = gs[0][rr][2 * 4 + hc] + gs[1][rr][2 * 4 + hc] + bfv[h];
        float go = gs[0][rr][3 * 4 + hc] + gs[1][rr][3 * 4 + hc] + bo[h];
        if (!FUSED) {
            const float* xr = xg + ((size_t)t * 32 + rr) * 4096;
            ga += xr[0 * 1024 + h];
            gi += xr[1 * 1024 + h];
            gf += xr[2 * 1024 + h];
            go += xr[3 * 1024 + h];
        }
        float a = tanh_f(ga);
        float i = sigm_f(gi);
        float f = sigm_f(gf);
        float o = sigm_f(go);
        float sprev = FIRST ? 0.f : sbuf[rr * 1024 + h];
        float s = a * i + sprev * f;
        sbuf[rr * 1024 + h] = s;
        float hv = tanh_f(s) * o;
        hnext[rr * 1024 + h] = hv;
        out[((size_t)rr * 512 + t) * 1024 + h] = hv;
    }
}

extern "C" void kernel_launch(void* const* d_in, const int* in_sizes, int n_in,
                              void* d_out, int out_size, void* d_ws, size_t ws_size,
                              hipStream_t stream)
{
    const float* X   = (const float*)d_in[0];
    const float* Wax = (const float*)d_in[1];
    const float* Wix = (const float*)d_in[2];
    const float* Wfx = (const float*)d_in[3];
    const float* Wox = (const float*)d_in[4];
    const float* Wah = (const float*)d_in[5];
    const float* Wih = (const float*)d_in[6];
    const float* Wfh = (const float*)d_in[7];
    const float* Woh = (const float*)d_in[8];
    const float* ba  = (const float*)d_in[9];
    const float* bi  = (const float*)d_in[10];
    const float* bfv = (const float*)d_in[11];
    const float* bo  = (const float*)d_in[12];
    float* out = (float*)d_out;

    const size_t XG_BYTES = (size_t)512 * 32 * 4096 * 4;   // 256 MiB
    const size_t HB = (size_t)32 * 1024 * 4;               // 128 KiB
    const bool big = ws_size >= XG_BYTES + 3 * HB;

    char* ws = (char*)d_ws;
    float *xg, *h0, *h1, *sb;
    if (big) {
        xg = (float*)ws;
        h0 = (float*)(ws + XG_BYTES);
        h1 = (float*)(ws + XG_BYTES + HB);
        sb = (float*)(ws + XG_BYTES + 2 * HB);
    } else {
        xg = nullptr;
        h0 = (float*)ws;
        h1 = (float*)(ws + HB);
        sb = (float*)(ws + 2 * HB);
    }

    if (big) {
        proj_kernel<<<16384, 256, 0, stream>>>(X, Wax, Wix, Wfx, Wox, xg);
    }

    float* hb[2] = { h0, h1 };
    for (int t = 0; t < 512; ++t) {
        const float* hprev = hb[(t + 1) & 1];
        float* hnext = hb[t & 1];
        if (big) {
            if (t == 0)
                step_kernel<true, false><<<256, 256, 0, stream>>>(hprev, hnext, sb, xg, X,
                    Wah, Wih, Wfh, Woh, Wax, Wix, Wfx, Wox, ba, bi, bfv, bo, out, t);
            else
                step_kernel<false, false><<<256, 256, 0, stream>>>(hprev, hnext, sb, xg, X,
                    Wah, Wih, Wfh, Woh, Wax, Wix, Wfx, Wox, ba, bi, bfv, bo, out, t);
        } else {
            if (t == 0)
                step_kernel<true, true><<<256, 256, 0, stream>>>(hprev, hnext, sb, xg, X,
                    Wah, Wih, Wfh, Woh, Wax, Wix, Wfx, Wox, ba, bi, bfv, bo, out, t);
            else
                step_kernel<false, true><<<256, 256, 0, stream>>>(hprev, hnext, sb, xg, X,
                    Wah, Wih, Wfh, Woh, Wax, Wix, Wfx, Wox, ba, bi, bfv, bo, out, t);
        }
    }
}

// Round 2
// 24008.675 us; speedup vs baseline: 2.6513x; 2.6513x over previous
//
#include <hip/hip_runtime.h>
#include <hip/hip_fp16.h>
#include <math.h>

// LSTM: B=32, T=512, D=1024, H=1024.
// Strategy: proj GEMM (fp32 in, fp16 out) -> persistent cooperative kernel for the
// 512 recurrent steps (W slice packed per block, h staged in LDS, s in registers,
// custom tree barrier between steps).

__device__ __forceinline__ float sigm_f(float x) {
    return 1.0f / (1.0f + __expf(-x));
}
__device__ __forceinline__ float tanh_f(float x) {
    return 1.0f - 2.0f / (__expf(2.0f * x) + 1.0f);
}

// ---------------- Projection GEMM (validated round 1; epilogue now fp16) -------
// xg[t][b][g*1024+c] = sum_d X[b][t][d] * Wx_g[d][c]
__global__ __launch_bounds__(256)
void proj_kernel(const float* __restrict__ X,
                 const float* __restrict__ Wa,
                 const float* __restrict__ Wi,
                 const float* __restrict__ Wf,
                 const float* __restrict__ Wo,
                 __half* __restrict__ xg)
{
    __shared__ float As[64][36];
    __shared__ float Bs[32][64];

    const int bx = blockIdx.x & 63;
    const int by = blockIdx.x >> 6;
    const int tid = threadIdx.x;
    const int tx = tid & 15, ty = tid >> 4;

    const int col0 = bx * 64;
    const int gate = col0 >> 10;
    const float* Wg = (gate == 0) ? Wa : ((gate == 1) ? Wi : ((gate == 2) ? Wf : Wo));
    const int wcol0 = col0 & 1023;
    const int row0 = by * 64;

    float acc[4][4];
#pragma unroll
    for (int i = 0; i < 4; i++)
#pragma unroll
        for (int j = 0; j < 4; j++) acc[i][j] = 0.f;

    for (int kt = 0; kt < 1024; kt += 32) {
#pragma unroll
        for (int u = 0; u < 2; u++) {
            int f4 = u * 256 + tid;
            int r  = f4 >> 3;
            int kq = (f4 & 7) << 2;
            float4 v = *reinterpret_cast<const float4*>(X + (size_t)(row0 + r) * 1024 + kt + kq);
            *reinterpret_cast<float4*>(&As[r][kq]) = v;
        }
#pragma unroll
        for (int u = 0; u < 2; u++) {
            int f4 = u * 256 + tid;
            int c4 = (f4 & 15) << 2;
            int kk = f4 >> 4;
            float4 v = *reinterpret_cast<const float4*>(Wg + (size_t)(kt + kk) * 1024 + wcol0 + c4);
            *reinterpret_cast<float4*>(&Bs[kk][c4]) = v;
        }
        __syncthreads();
#pragma unroll
        for (int kk = 0; kk < 32; kk++) {
            float a0 = As[ty * 4 + 0][kk];
            float a1 = As[ty * 4 + 1][kk];
            float a2 = As[ty * 4 + 2][kk];
            float a3 = As[ty * 4 + 3][kk];
            float4 b = *reinterpret_cast<const float4*>(&Bs[kk][tx * 4]);
            acc[0][0] += a0 * b.x; acc[0][1] += a0 * b.y; acc[0][2] += a0 * b.z; acc[0][3] += a0 * b.w;
            acc[1][0] += a1 * b.x; acc[1][1] += a1 * b.y; acc[1][2] += a1 * b.z; acc[1][3] += a1 * b.w;
            acc[2][0] += a2 * b.x; acc[2][1] += a2 * b.y; acc[2][2] += a2 * b.z; acc[2][3] += a2 * b.w;
            acc[3][0] += a3 * b.x; acc[3][1] += a3 * b.y; acc[3][2] += a3 * b.z; acc[3][3] += a3 * b.w;
        }
        __syncthreads();
    }
#pragma unroll
    for (int i = 0; i < 4; i++) {
        int r = row0 + ty * 4 + i;
        int b = r >> 9, t = r & 511;
        ushort4 v;
        v.x = __half_as_ushort(__float2half_rn(acc[i][0]));
        v.y = __half_as_ushort(__float2half_rn(acc[i][1]));
        v.z = __half_as_ushort(__float2half_rn(acc[i][2]));
        v.w = __half_as_ushort(__float2half_rn(acc[i][3]));
        *reinterpret_cast<ushort4*>((unsigned short*)xg + ((size_t)t * 32 + b) * 4096 + col0 + tx * 4) = v;
    }
}

// ---------------- Persistent recurrent kernel ----------------
// 256 blocks x 512 threads (cooperative). Block blk owns h-cols [blk*4, blk*4+4).
// thread: ks = tid&15 (K split, 64 k's each, interleaved in chunks of 4),
//         row = tid>>4 (0..31). 16 accumulators (4 gates x 4 cols).
// Wh slice packed once into wpack[blk] so inner-loop wave loads are contiguous.
__global__ __launch_bounds__(512)
void lstm_persist(const __half* __restrict__ xg,          // [512][32][4096] fp16
                  const float* __restrict__ Wah, const float* __restrict__ Wih,
                  const float* __restrict__ Wfh, const float* __restrict__ Woh,
                  const float* __restrict__ ba, const float* __restrict__ bi,
                  const float* __restrict__ bfv, const float* __restrict__ bo,
                  float* __restrict__ wpack,               // [256][16384]
                  float* __restrict__ hA, float* __restrict__ hB,  // [32][1024] each
                  unsigned* __restrict__ flags,            // [256], pre-zeroed
                  unsigned* __restrict__ go,               // [1], pre-zeroed
                  float* __restrict__ out)                 // [32][512][1024]
{
    __shared__ float  hs[32 * 1028];       // h staged, padded row stride
    __shared__ unsigned short xbuf[32][16];

    const int tid = threadIdx.x;
    const int blk = blockIdx.x;
    const int hc0 = blk * 4;
    const int ks  = tid & 15;
    const int row = tid >> 4;

    // ---- phase 0: pack this block's W slice: wpack[blk][((j*4+kk)*4+g)*16+ks][4]
    //      content = W{g}_h[4*(ks+16j)+kk][hc0 .. hc0+3]
    float* wblk = wpack + (size_t)blk * 16384;
#pragma unroll
    for (int u = 0; u < 8; ++u) {
        int flat = u * 512 + tid;            // 0..4095 (float4 index)
        int ks2  = flat & 15;
        int g    = (flat >> 4) & 3;
        int kk   = (flat >> 6) & 3;
        int j    = flat >> 8;
        int k    = 4 * (ks2 + 16 * j) + kk;
        const float* Wg = (g == 0) ? Wah : ((g == 1) ? Wih : ((g == 2) ? Wfh : Woh));
        float4 v = *reinterpret_cast<const float4*>(Wg + (size_t)k * 1024 + hc0);
        *reinterpret_cast<float4*>(wblk + (size_t)flat * 4) = v;
    }

    // bias registers (c = g*4+hc)
    float biasr[16];
#pragma unroll
    for (int hc = 0; hc < 4; ++hc) {
        biasr[0 + hc]  = ba [hc0 + hc];
        biasr[4 + hc]  = bi [hc0 + hc];
        biasr[8 + hc]  = bfv[hc0 + hc];
        biasr[12 + hc] = bo [hc0 + hc];
    }
    float sreg[4] = {0.f, 0.f, 0.f, 0.f};

    __syncthreads();   // wpack visible block-wide (same CU)

    for (int t = 0; t < 512; ++t) {
        if (t > 0) {
            // ---- tree barrier #t (release h_{t-1}, acquire before reading) ----
            __syncthreads();                       // all stores drained (vmcnt before s_barrier)
            if (tid == 0) {
                __threadfence();                   // release: push h writes to coherent point
                if (blk != 0) {
                    __hip_atomic_store(&flags[blk], (unsigned)t, __ATOMIC_RELAXED, __HIP_MEMORY_SCOPE_AGENT);
                    while (__hip_atomic_load(go, __ATOMIC_RELAXED, __HIP_MEMORY_SCOPE_AGENT) < (unsigned)t)
                        __builtin_amdgcn_s_sleep(1);
                }
            }
            if (blk == 0) {
                if (tid >= 1 && tid < 256) {
                    while (__hip_atomic_load(&flags[tid], __ATOMIC_RELAXED, __HIP_MEMORY_SCOPE_AGENT) < (unsigned)t)
                        __builtin_amdgcn_s_sleep(1);
                }
                __syncthreads();
                if (tid == 0)
                    __hip_atomic_store(go, (unsigned)t, __ATOMIC_RELAXED, __HIP_MEMORY_SCOPE_AGENT);
            }
            if (tid == 0) __threadfence();         // acquire: invalidate L1/L2 before h reads
            __syncthreads();
        }

        const float* hprev = (t & 1) ? hA : hB;    // t=1 reads hA (written at t=0)
        float*       hnext = (t & 1) ? hB : hA;

        // ---- stage h_prev into LDS (coalesced) ----
        if (t > 0) {
            const float4* hp = reinterpret_cast<const float4*>(hprev);
#pragma unroll
            for (int u = 0; u < 16; ++u) {
                int idx = u * 512 + tid;           // 0..8191 float4s
                int r   = idx >> 8;
                int c4  = idx & 255;
                float4 v = hp[idx];
                *reinterpret_cast<float4*>(&hs[r * 1028 + c4 * 4]) = v;
            }
        }
        // ---- stage xg tile (fp16, 2KB) ----
        if (tid < 128) {
            int r = tid >> 2, g = tid & 3;
            ushort4 v = *reinterpret_cast<const ushort4*>(
                (const unsigned short*)xg + ((size_t)t * 32 + r) * 4096 + g * 1024 + hc0);
            *reinterpret_cast<ushort4*>(&xbuf[r][g * 4]) = v;
        }
        __syncthreads();

        // ---- dot: g[row][c] partial over this thread's 64 k's ----
        float acc[16];
#pragma unroll
        for (int c = 0; c < 16; ++c) acc[c] = 0.f;

        if (t > 0) {
#pragma unroll 4
            for (int j = 0; j < 16; ++j) {
                const float4 hv = *reinterpret_cast<const float4*>(&hs[row * 1028 + (ks + 16 * j) * 4]);
                const float* wj = wblk + j * 1024 + ks * 4;
#pragma unroll
                for (int kk = 0; kk < 4; ++kk) {
                    float a = (kk == 0) ? hv.x : ((kk == 1) ? hv.y : ((kk == 2) ? hv.z : hv.w));
#pragma unroll
                    for (int g = 0; g < 4; ++g) {
                        float4 w = *reinterpret_cast<const float4*>(wj + kk * 256 + g * 64);
                        acc[g * 4 + 0] += a * w.x;
                        acc[g * 4 + 1] += a * w.y;
                        acc[g * 4 + 2] += a * w.z;
                        acc[g * 4 + 3] += a * w.w;
                    }
                }
            }
        }

        // ---- 16-way K reduction via shfl (groups of 16 lanes, same wave) ----
#pragma unroll
        for (int m = 1; m <= 8; m <<= 1) {
#pragma unroll
            for (int c = 0; c < 16; ++c)
                acc[c] += __shfl_xor(acc[c], m, 64);
        }

        // ---- leader: gates, state update, write h + out ----
        if (ks == 0) {
            float hv4[4];
#pragma unroll
            for (int hc = 0; hc < 4; ++hc) {
                float ga = acc[0 + hc]  + biasr[0 + hc]  + __half2float(__ushort_as_half(xbuf[row][0 + hc]));
                float gi = acc[4 + hc]  + biasr[4 + hc]  + __half2float(__ushort_as_half(xbuf[row][4 + hc]));
                float gf = acc[8 + hc]  + biasr[8 + hc]  + __half2float(__ushort_as_half(xbuf[row][8 + hc]));
                float gO = acc[12 + hc] + biasr[12 + hc] + __half2float(__ushort_as_half(xbuf[row][12 + hc]));
                float a  = tanh_f(ga);
                float ii = sigm_f(gi);
                float ff = sigm_f(gf);
                float oo = sigm_f(gO);
                sreg[hc] = a * ii + sreg[hc] * ff;
                hv4[hc]  = tanh_f(sreg[hc]) * oo;
            }
            float4 v = make_float4(hv4[0], hv4[1], hv4[2], hv4[3]);
            *reinterpret_cast<float4*>(hnext + row * 1024 + hc0) = v;
            *reinterpret_cast<float4*>(out + ((size_t)row * 512 + t) * 1024 + hc0) = v;
        }
    }
}

// ---------------- Fallback per-step kernel (round-1, FUSED path) ----------------
template<bool FIRST>
__global__ __launch_bounds__(256)
void step_kernel(const float* __restrict__ hprev, float* __restrict__ hnext,
                 float* __restrict__ sbuf, const float* __restrict__ X,
                 const float* __restrict__ Wah, const float* __restrict__ Wih,
                 const float* __restrict__ Wfh, const float* __restrict__ Woh,
                 const float* __restrict__ Wax, const float* __restrict__ Wix,
                 const float* __restrict__ Wfx, const float* __restrict__ Wox,
                 const float* __restrict__ ba, const float* __restrict__ bi,
                 const float* __restrict__ bfv, const float* __restrict__ bo,
                 float* __restrict__ out, int t)
{
    __shared__ float hs[32 * 1028];
    __shared__ float gs[2][32][16];

    const int tid  = threadIdx.x;
    const int hc0  = blockIdx.x * 4;
    const int kh   = tid >> 7;
    const int gtid = tid & 127;
    const int r    = gtid >> 2;
    const int gate = gtid & 3;
    const int k0   = kh * 512;

    float4 acc = make_float4(0.f, 0.f, 0.f, 0.f);

    if (!FIRST) {
        for (int u = 0; u < 32; u++) {
            int f4 = u * 256 + tid;
            int rr = f4 >> 8;
            int kq = (f4 & 255) << 2;
            float4 v = *reinterpret_cast<const float4*>(hprev + rr * 1024 + kq);
            *reinterpret_cast<float4*>(&hs[rr * 1028 + kq]) = v;
        }
        __syncthreads();
        const float* Wg = (gate == 0) ? Wah : ((gate == 1) ? Wih : ((gate == 2) ? Wfh : Woh));
        const float* Wp = Wg + hc0;
#pragma unroll 4
        for (int k = k0; k < k0 + 512; k += 4) {
            float4 hv = *reinterpret_cast<const float4*>(&hs[r * 1028 + k]);
            float4 w0 = *reinterpret_cast<const float4*>(Wp + (size_t)(k + 0) * 1024);
            float4 w1 = *reinterpret_cast<const float4*>(Wp + (size_t)(k + 1) * 1024);
            float4 w2 = *reinterpret_cast<const float4*>(Wp + (size_t)(k + 2) * 1024);
            float4 w3 = *reinterpret_cast<const float4*>(Wp + (size_t)(k + 3) * 1024);
            acc.x += hv.x * w0.x + hv.y * w1.x + hv.z * w2.x + hv.w * w3.x;
            acc.y += hv.x * w0.y + hv.y * w1.y + hv.z * w2.y + hv.w * w3.y;
            acc.z += hv.x * w0.z + hv.y * w1.z + hv.z * w2.z + hv.w * w3.z;
            acc.w += hv.x * w0.w + hv.y * w1.w + hv.z * w2.w + hv.w * w3.w;
        }
    }
    {
        __syncthreads();
        for (int u = 0; u < 32; u++) {
            int f4 = u * 256 + tid;
            int rr = f4 >> 8;
            int kq = (f4 & 255) << 2;
            float4 v = *reinterpret_cast<const float4*>(X + ((size_t)rr * 512 + t) * 1024 + kq);
            *reinterpret_cast<float4*>(&hs[rr * 1028 + kq]) = v;
        }
        __syncthreads();
        const float* Wg = (gate == 0) ? Wax : ((gate == 1) ? Wix : ((gate == 2) ? Wfx : Wox));
        const float* Wp = Wg + hc0;
#pragma unroll 4
        for (int k = k0; k < k0 + 512; k += 4) {
            float4 hv = *reinterpret_cast<const float4*>(&hs[r * 1028 + k]);
            float4 w0 = *reinterpret_cast<const float4*>(Wp + (size_t)(k + 0) * 1024);
            float4 w1 = *reinterpret_cast<const float4*>(Wp + (size_t)(k + 1) * 1024);
            float4 w2 = *reinterpret_cast<const float4*>(Wp + (size_t)(k + 2) * 1024);
            float4 w3 = *reinterpret_cast<const float4*>(Wp + (size_t)(k + 3) * 1024);
            acc.x += hv.x * w0.x + hv.y * w1.x + hv.z * w2.x + hv.w * w3.x;
            acc.y += hv.x * w0.y + hv.y * w1.y + hv.z * w2.y + hv.w * w3.y;
            acc.z += hv.x * w0.z + hv.y * w1.z + hv.z * w2.z + hv.w * w3.z;
            acc.w += hv.x * w0.w + hv.y * w1.w + hv.z * w2.w + hv.w * w3.w;
        }
    }

    *reinterpret_cast<float4*>(&gs[kh][r][gate * 4]) = acc;
    __syncthreads();

    if (tid < 128) {
        const int rr = tid >> 2;
        const int hc = tid & 3;
        const int h  = hc0 + hc;
        float ga = gs[0][rr][0 + hc]  + gs[1][rr][0 + hc]  + ba[h];
        float gi = gs[0][rr][4 + hc]  + gs[1][rr][4 + hc]  + bi[h];
        float gf = gs[0][rr][8 + hc]  + gs[1][rr][8 + hc]  + bfv[h];
        float gO = gs[0][rr][12 + hc] + gs[1][rr][12 + hc] + bo[h];
        float a = tanh_f(ga);
        float i = sigm_f(gi);
        float f = sigm_f(gf);
        float o = sigm_f(gO);
        float sprev = FIRST ? 0.f : sbuf[rr * 1024 + h];
        float s = a * i + sprev * f;
        sbuf[rr * 1024 + h] = s;
        float hv = tanh_f(s) * o;
        hnext[rr * 1024 + h] = hv;
        out[((size_t)rr * 512 + t) * 1024 + h] = hv;
    }
}

extern "C" void kernel_launch(void* const* d_in, const int* in_sizes, int n_in,
                              void* d_out, int out_size, void* d_ws, size_t ws_size,
                              hipStream_t stream)
{
    const float* X   = (const float*)d_in[0];
    const float* Wax = (const float*)d_in[1];
    const float* Wix = (const float*)d_in[2];
    const float* Wfx = (const float*)d_in[3];
    const float* Wox = (const float*)d_in[4];
    const float* Wah = (const float*)d_in[5];
    const float* Wih = (const float*)d_in[6];
    const float* Wfh = (const float*)d_in[7];
    const float* Woh = (const float*)d_in[8];
    const float* ba  = (const float*)d_in[9];
    const float* bi  = (const float*)d_in[10];
    const float* bfv = (const float*)d_in[11];
    const float* bo  = (const float*)d_in[12];
    float* out = (float*)d_out;

    const size_t XGH   = (size_t)512 * 32 * 4096 * 2;   // 128 MiB (fp16 xg)
    const size_t WPACK = (size_t)256 * 16384 * 4;       // 16 MiB
    const size_t HB    = (size_t)32 * 1024 * 4;         // 128 KiB
    const size_t BAR   = 4096;

    char* ws = (char*)d_ws;
    const bool big = ws_size >= XGH + WPACK + 2 * HB + BAR;

    if (big) {
        __half*   xg    = (__half*)ws;
        float*    wpack = (float*)(ws + XGH);
        float*    hA    = (float*)(ws + XGH + WPACK);
        float*    hB    = (float*)(ws + XGH + WPACK + HB);
        unsigned* flags = (unsigned*)(ws + XGH + WPACK + 2 * HB);
        unsigned* go    = flags + 256;

        hipMemsetAsync(flags, 0, BAR, stream);
        proj_kernel<<<16384, 256, 0, stream>>>(X, Wax, Wix, Wfx, Wox, xg);

        void* args[] = {
            (void*)&xg,
            (void*)&Wah, (void*)&Wih, (void*)&Wfh, (void*)&Woh,
            (void*)&ba, (void*)&bi, (void*)&bfv, (void*)&bo,
            (void*)&wpack, (void*)&hA, (void*)&hB,
            (void*)&flags, (void*)&go, (void*)&out
        };
        hipLaunchCooperativeKernel((void*)lstm_persist, dim3(256), dim3(512),
                                   args, 0, stream);
    } else {
        float* h0 = (float*)ws;
        float* h1 = (float*)(ws + HB);
        float* sb = (float*)(ws + 2 * HB);
        float* hb[2] = { h0, h1 };
        for (int t = 0; t < 512; ++t) {
            const float* hprev = hb[(t + 1) & 1];
            float* hnext = hb[t & 1];
            if (t == 0)
                step_kernel<true><<<256, 256, 0, stream>>>(hprev, hnext, sb, X,
                    Wah, Wih, Wfh, Woh, Wax, Wix, Wfx, Wox, ba, bi, bfv, bo, out, t);
            else
                step_kernel<false><<<256, 256, 0, stream>>>(hprev, hnext, sb, X,
                    Wah, Wih, Wfh, Woh, Wax, Wix, Wfx, Wox, ba, bi, bfv, bo, out, t);
        }
    }
}

// Round 3
// 3772.351 us; speedup vs baseline: 16.8740x; 6.3644x over previous
//
#include <hip/hip_runtime.h>
#include <hip/hip_fp16.h>

// LSTM: B=32, T=512, D=1024, H=1024.
// proj GEMM (fp32 VALU, fp16 out) -> persistent cooperative MFMA kernel for the
// 512 recurrent steps. Fenceless cross-XCD coherence: h traffic via sc0/sc1
// (system-coherent) loads/stores; flags via agent-scope atomics; NO threadfence
// (avoids per-step full-L2 writeback/invalidate that cost ~40us/step in round 2).

typedef __attribute__((ext_vector_type(8))) short bf16x8;
typedef __attribute__((ext_vector_type(4))) float f32x4;

__device__ __forceinline__ float sigm_f(float x) { return 1.0f / (1.0f + __expf(-x)); }
__device__ __forceinline__ float tanh_f(float x) { return 1.0f - 2.0f / (__expf(2.0f * x) + 1.0f); }

__device__ __forceinline__ unsigned short f2bf(float x) {
    unsigned u = __float_as_uint(x);
    u += 0x7FFFu + ((u >> 16) & 1u);      // RNE
    return (unsigned short)(u >> 16);
}

// system-coherent 16B load: issued WITHOUT wait; caller must s_waitcnt vmcnt(0)
// + sched_barrier(0) before consuming (rule: compiler hoists reg-ops past asm waitcnt).
__device__ __forceinline__ void ld_sys_b128(bf16x8& d, const void* p) {
    asm volatile("global_load_dwordx4 %0, %1, off sc0 sc1" : "=v"(d) : "v"(p) : "memory");
}
__device__ __forceinline__ void st_sys_u16(void* p, unsigned v) {
    asm volatile("global_store_short %0, %1, off sc0 sc1" :: "v"(p), "v"(v) : "memory");
}

// ---------------- Projection GEMM (validated rounds 1-2) ----------------
__global__ __launch_bounds__(256)
void proj_kernel(const float* __restrict__ X,
                 const float* __restrict__ Wa,
                 const float* __restrict__ Wi,
                 const float* __restrict__ Wf,
                 const float* __restrict__ Wo,
                 __half* __restrict__ xg)
{
    __shared__ float As[64][36];
    __shared__ float Bs[32][64];

    const int bx = blockIdx.x & 63;
    const int by = blockIdx.x >> 6;
    const int tid = threadIdx.x;
    const int tx = tid & 15, ty = tid >> 4;

    const int col0 = bx * 64;
    const int gate = col0 >> 10;
    const float* Wg = (gate == 0) ? Wa : ((gate == 1) ? Wi : ((gate == 2) ? Wf : Wo));
    const int wcol0 = col0 & 1023;
    const int row0 = by * 64;

    float acc[4][4];
#pragma unroll
    for (int i = 0; i < 4; i++)
#pragma unroll
        for (int j = 0; j < 4; j++) acc[i][j] = 0.f;

    for (int kt = 0; kt < 1024; kt += 32) {
#pragma unroll
        for (int u = 0; u < 2; u++) {
            int f4 = u * 256 + tid;
            int r  = f4 >> 3;
            int kq = (f4 & 7) << 2;
            float4 v = *reinterpret_cast<const float4*>(X + (size_t)(row0 + r) * 1024 + kt + kq);
            *reinterpret_cast<float4*>(&As[r][kq]) = v;
        }
#pragma unroll
        for (int u = 0; u < 2; u++) {
            int f4 = u * 256 + tid;
            int c4 = (f4 & 15) << 2;
            int kk = f4 >> 4;
            float4 v = *reinterpret_cast<const float4*>(Wg + (size_t)(kt + kk) * 1024 + wcol0 + c4);
            *reinterpret_cast<float4*>(&Bs[kk][c4]) = v;
        }
        __syncthreads();
#pragma unroll
        for (int kk = 0; kk < 32; kk++) {
            float a0 = As[ty * 4 + 0][kk];
            float a1 = As[ty * 4 + 1][kk];
            float a2 = As[ty * 4 + 2][kk];
            float a3 = As[ty * 4 + 3][kk];
            float4 b = *reinterpret_cast<const float4*>(&Bs[kk][tx * 4]);
            acc[0][0] += a0 * b.x; acc[0][1] += a0 * b.y; acc[0][2] += a0 * b.z; acc[0][3] += a0 * b.w;
            acc[1][0] += a1 * b.x; acc[1][1] += a1 * b.y; acc[1][2] += a1 * b.z; acc[1][3] += a1 * b.w;
            acc[2][0] += a2 * b.x; acc[2][1] += a2 * b.y; acc[2][2] += a2 * b.z; acc[2][3] += a2 * b.w;
            acc[3][0] += a3 * b.x; acc[3][1] += a3 * b.y; acc[3][2] += a3 * b.z; acc[3][3] += a3 * b.w;
        }
        __syncthreads();
    }
#pragma unroll
    for (int i = 0; i < 4; i++) {
        int r = row0 + ty * 4 + i;
        int b = r >> 9, t = r & 511;
        ushort4 v;
        v.x = __half_as_ushort(__float2half_rn(acc[i][0]));
        v.y = __half_as_ushort(__float2half_rn(acc[i][1]));
        v.z = __half_as_ushort(__float2half_rn(acc[i][2]));
        v.w = __half_as_ushort(__float2half_rn(acc[i][3]));
        *reinterpret_cast<ushort4*>((unsigned short*)xg + ((size_t)t * 32 + b) * 4096 + col0 + tx * 4) = v;
    }
}

// ---------------- Persistent MFMA recurrent kernel ----------------
// 256 blocks x 512 threads. Block blk owns h-cols [blk*4, blk*4+4) -> 16 gate-cols.
// Per step: g[32][16] = h[32][1024] @ Wslice[1024][16] via mfma_f32_16x16x32_bf16.
// K split over 8 waves (4 K-iters each, 2 M-tiles) -> LDS partial reduce.
// h published as bf16, layout [koct 128][row 32][8] so A-frags are 16B coherent loads.
__global__ __launch_bounds__(512)
void lstm_persist(const unsigned short* __restrict__ xg,   // [512][32][4096] fp16
                  const float* __restrict__ Wah, const float* __restrict__ Wih,
                  const float* __restrict__ Wfh, const float* __restrict__ Woh,
                  const float* __restrict__ ba, const float* __restrict__ bi,
                  const float* __restrict__ bfv, const float* __restrict__ bo,
                  unsigned short* __restrict__ wpk,        // [256][16384] bf16 B-frag order
                  unsigned short* __restrict__ h16A,       // [128][32][8] bf16
                  unsigned short* __restrict__ h16B,
                  unsigned* __restrict__ flags,            // [256] pre-zeroed
                  unsigned* __restrict__ go,               // [1] pre-zeroed
                  float* __restrict__ out)                 // [32][512][1024]
{
    __shared__ float pbuf[16 * 64 * 4];          // [wv*2+m][lane][reg] fp32 partials (16 KB)
    __shared__ float gbuf[32 * 16];              // g[row][col] reduced
    __shared__ unsigned short xbuf[32][16];

    const int tid  = threadIdx.x;
    const int blk  = blockIdx.x;
    const int hc0  = blk * 4;
    const int wv   = tid >> 6;                   // wave 0..7
    const int lane = tid & 63;

    // ---- pack this block's Wh slice into B-fragment order (once) ----
    // wpk quad fq=(kiter*64+lane): 8 bf16 = W[kiter*32+(lane>>4)*8+e][col=lane&15]
    unsigned short* wb = wpk + (size_t)blk * 16384;
#pragma unroll
    for (int q = 0; q < 4; ++q) {
        int fq    = tid * 4 + q;                 // 0..2047
        int kiter = fq >> 6;
        int ln    = fq & 63;
        int col   = ln & 15;
        int g     = col >> 2, c = col & 3;
        int kbase = kiter * 32 + (ln >> 4) * 8;
        const float* Wg = (g == 0) ? Wah : ((g == 1) ? Wih : ((g == 2) ? Wfh : Woh));
        unsigned short tmp[8];
#pragma unroll
        for (int e = 0; e < 8; ++e)
            tmp[e] = f2bf(Wg[(size_t)(kbase + e) * 1024 + hc0 + c]);
        *reinterpret_cast<int4*>(wb + (size_t)fq * 8) = *reinterpret_cast<int4*>(tmp);
    }

    // gate-thread persistent state
    float biasr[4][4];                           // [gate][hc]
    float sreg[4] = {0.f, 0.f, 0.f, 0.f};
    if (tid < 128) {
        int hc = tid & 3;
        biasr[0][hc] = ba [hc0 + hc];            // note: only [._][tid&3] used per thread
        biasr[1][hc] = bi [hc0 + hc];
        biasr[2][hc] = bfv[hc0 + hc];
        biasr[3][hc] = bo [hc0 + hc];
    }

    __syncthreads();                             // wpk visible block-wide

    const int koct = lane >> 4;                  // 0..3
    const int arow = lane & 15;

    for (int t = 0; t < 512; ++t) {
        if (t > 0) {
            // ---- fenceless grid barrier (h stores are sc0/sc1 -> at IC before
            //      the pre-s_barrier vmcnt drain lets any wave past) ----
            __syncthreads();
            if (blk != 0) {
                if (tid == 0) {
                    __hip_atomic_store(&flags[blk], (unsigned)t, __ATOMIC_RELAXED, __HIP_MEMORY_SCOPE_AGENT);
                    while (__hip_atomic_load(go, __ATOMIC_RELAXED, __HIP_MEMORY_SCOPE_AGENT) < (unsigned)t)
                        __builtin_amdgcn_s_sleep(2);
                }
            } else {
                if (tid >= 1 && tid < 256) {
                    while (__hip_atomic_load(&flags[tid], __ATOMIC_RELAXED, __HIP_MEMORY_SCOPE_AGENT) < (unsigned)t)
                        __builtin_amdgcn_s_sleep(2);
                }
                __syncthreads();
                if (tid == 0)
                    __hip_atomic_store(go, (unsigned)t, __ATOMIC_RELAXED, __HIP_MEMORY_SCOPE_AGENT);
            }
            __syncthreads();
        }

        const unsigned short* hp = (t & 1) ? h16A : h16B;   // t=1 reads h16A (written t=0)
        unsigned short*       hn = (t & 1) ? h16B : h16A;

        // stage xg tile (cached loads; xg never changes during kernel)
        if (tid < 128) {
            int r = tid >> 2, g = tid & 3;
            ushort4 v = *reinterpret_cast<const ushort4*>(
                xg + ((size_t)t * 32 + r) * 4096 + g * 1024 + hc0);
            *reinterpret_cast<ushort4*>(&xbuf[r][g * 4]) = v;
        }

        if (t > 0) {
            // ---- issue A (coherent) and B (cached) fragment loads ----
            bf16x8 a0[4], a1[4], b[4];
#pragma unroll
            for (int ki = 0; ki < 4; ++ki) {
                int kit = wv * 4 + ki;
                int oct = kit * 4 + koct;
                ld_sys_b128(a0[ki], hp + ((size_t)(oct * 32 + arow) * 8));
                ld_sys_b128(a1[ki], hp + ((size_t)(oct * 32 + arow + 16) * 8));
                b[ki] = *reinterpret_cast<const bf16x8*>(wb + ((size_t)(kit * 64 + lane) * 8));
            }
            asm volatile("s_waitcnt vmcnt(0)" ::: "memory");
            __builtin_amdgcn_sched_barrier(0);

            f32x4 acc0 = {0.f, 0.f, 0.f, 0.f};
            f32x4 acc1 = {0.f, 0.f, 0.f, 0.f};
#pragma unroll
            for (int ki = 0; ki < 4; ++ki) {
                acc0 = __builtin_amdgcn_mfma_f32_16x16x32_bf16(a0[ki], b[ki], acc0, 0, 0, 0);
                acc1 = __builtin_amdgcn_mfma_f32_16x16x32_bf16(a1[ki], b[ki], acc1, 0, 0, 0);
            }
            *reinterpret_cast<f32x4*>(&pbuf[((wv * 2 + 0) * 64 + lane) * 4]) = acc0;
            *reinterpret_cast<f32x4*>(&pbuf[((wv * 2 + 1) * 64 + lane) * 4]) = acc1;
        }
        __syncthreads();

        if (t > 0) {
            // reduce 8 wave-partials: tid -> (m, ln, rg)
            int m  = tid >> 8;
            int ln = (tid >> 2) & 63;
            int rg = tid & 3;
            float s = 0.f;
#pragma unroll
            for (int w = 0; w < 8; ++w)
                s += pbuf[((w * 2 + m) * 64 + ln) * 4 + rg];
            int row = m * 16 + (ln >> 4) * 4 + rg;     // D-frag: col=lane&15, row=(lane>>4)*4+reg
            int col = ln & 15;
            gbuf[row * 16 + col] = s;
        }
        __syncthreads();

        if (tid < 128) {
            const int row = tid >> 2;
            const int hc  = tid & 3;
            float ga = (t > 0 ? gbuf[row * 16 + 0 * 4 + hc] : 0.f) + biasr[0][hc]
                     + __half2float(__ushort_as_half(xbuf[row][0 * 4 + hc]));
            float gi = (t > 0 ? gbuf[row * 16 + 1 * 4 + hc] : 0.f) + biasr[1][hc]
                     + __half2float(__ushort_as_half(xbuf[row][1 * 4 + hc]));
            float gf = (t > 0 ? gbuf[row * 16 + 2 * 4 + hc] : 0.f) + biasr[2][hc]
                     + __half2float(__ushort_as_half(xbuf[row][2 * 4 + hc]));
            float gO = (t > 0 ? gbuf[row * 16 + 3 * 4 + hc] : 0.f) + biasr[3][hc]
                     + __half2float(__ushort_as_half(xbuf[row][3 * 4 + hc]));
            float a  = tanh_f(ga);
            float ii = sigm_f(gi);
            float ff = sigm_f(gf);
            float oo = sigm_f(gO);
            sreg[0] = a * ii + sreg[0] * ff;     // per-thread scalar state (use slot 0)
            float hv = tanh_f(sreg[0]) * oo;

            out[((size_t)row * 512 + t) * 1024 + hc0 + hc] = hv;   // normal cached store
            int colg = hc0 + hc;
            st_sys_u16(hn + ((size_t)((colg >> 3) * 32 + row) * 8 + (colg & 7)),
                       (unsigned)f2bf(hv));
        }
        // next iteration's pre-barrier __syncthreads drains the h stores (vmcnt0/wave)
    }
}

// ---------------- Fallback per-step kernel (round-1, FUSED path) ----------------
template<bool FIRST>
__global__ __launch_bounds__(256)
void step_kernel(const float* __restrict__ hprev, float* __restrict__ hnext,
                 float* __restrict__ sbuf, const float* __restrict__ X,
                 const float* __restrict__ Wah, const float* __restrict__ Wih,
                 const float* __restrict__ Wfh, const float* __restrict__ Woh,
                 const float* __restrict__ Wax, const float* __restrict__ Wix,
                 const float* __restrict__ Wfx, const float* __restrict__ Wox,
                 const float* __restrict__ ba, const float* __restrict__ bi,
                 const float* __restrict__ bfv, const float* __restrict__ bo,
                 float* __restrict__ out, int t)
{
    __shared__ float hs[32 * 1028];
    __shared__ float gs[2][32][16];

    const int tid  = threadIdx.x;
    const int hc0  = blockIdx.x * 4;
    const int kh   = tid >> 7;
    const int gtid = tid & 127;
    const int r    = gtid >> 2;
    const int gate = gtid & 3;
    const int k0   = kh * 512;

    float4 acc = make_float4(0.f, 0.f, 0.f, 0.f);

    if (!FIRST) {
        for (int u = 0; u < 32; u++) {
            int f4 = u * 256 + tid;
            int rr = f4 >> 8;
            int kq = (f4 & 255) << 2;
            float4 v = *reinterpret_cast<const float4*>(hprev + rr * 1024 + kq);
            *reinterpret_cast<float4*>(&hs[rr * 1028 + kq]) = v;
        }
        __syncthreads();
        const float* Wg = (gate == 0) ? Wah : ((gate == 1) ? Wih : ((gate == 2) ? Wfh : Woh));
        const float* Wp = Wg + hc0;
#pragma unroll 4
        for (int k = k0; k < k0 + 512; k += 4) {
            float4 hv = *reinterpret_cast<const float4*>(&hs[r * 1028 + k]);
            float4 w0 = *reinterpret_cast<const float4*>(Wp + (size_t)(k + 0) * 1024);
            float4 w1 = *reinterpret_cast<const float4*>(Wp + (size_t)(k + 1) * 1024);
            float4 w2 = *reinterpret_cast<const float4*>(Wp + (size_t)(k + 2) * 1024);
            float4 w3 = *reinterpret_cast<const float4*>(Wp + (size_t)(k + 3) * 1024);
            acc.x += hv.x * w0.x + hv.y * w1.x + hv.z * w2.x + hv.w * w3.x;
            acc.y += hv.x * w0.y + hv.y * w1.y + hv.z * w2.y + hv.w * w3.y;
            acc.z += hv.x * w0.z + hv.y * w1.z + hv.z * w2.z + hv.w * w3.z;
            acc.w += hv.x * w0.w + hv.y * w1.w + hv.z * w2.w + hv.w * w3.w;
        }
    }
    {
        __syncthreads();
        for (int u = 0; u < 32; u++) {
            int f4 = u * 256 + tid;
            int rr = f4 >> 8;
            int kq = (f4 & 255) << 2;
            float4 v = *reinterpret_cast<const float4*>(X + ((size_t)rr * 512 + t) * 1024 + kq);
            *reinterpret_cast<float4*>(&hs[rr * 1028 + kq]) = v;
        }
        __syncthreads();
        const float* Wg = (gate == 0) ? Wax : ((gate == 1) ? Wix : ((gate == 2) ? Wfx : Wox));
        const float* Wp = Wg + hc0;
#pragma unroll 4
        for (int k = k0; k < k0 + 512; k += 4) {
            float4 hv = *reinterpret_cast<const float4*>(&hs[r * 1028 + k]);
            float4 w0 = *reinterpret_cast<const float4*>(Wp + (size_t)(k + 0) * 1024);
            float4 w1 = *reinterpret_cast<const float4*>(Wp + (size_t)(k + 1) * 1024);
            float4 w2 = *reinterpret_cast<const float4*>(Wp + (size_t)(k + 2) * 1024);
            float4 w3 = *reinterpret_cast<const float4*>(Wp + (size_t)(k + 3) * 1024);
            acc.x += hv.x * w0.x + hv.y * w1.x + hv.z * w2.x + hv.w * w3.x;
            acc.y += hv.x * w0.y + hv.y * w1.y + hv.z * w2.y + hv.w * w3.y;
            acc.z += hv.x * w0.z + hv.y * w1.z + hv.z * w2.z + hv.w * w3.z;
            acc.w += hv.x * w0.w + hv.y * w1.w + hv.z * w2.w + hv.w * w3.w;
        }
    }

    *reinterpret_cast<float4*>(&gs[kh][r][gate * 4]) = acc;
    __syncthreads();

    if (tid < 128) {
        const int rr = tid >> 2;
        const int hc = tid & 3;
        const int h  = hc0 + hc;
        float ga = gs[0][rr][0 + hc]  + gs[1][rr][0 + hc]  + ba[h];
        float gi = gs[0][rr][4 + hc]  + gs[1][rr][4 + hc]  + bi[h];
        float gf = gs[0][rr][8 + hc]  + gs[1][rr][8 + hc]  + bfv[h];
        float gO = gs[0][rr][12 + hc] + gs[1][rr][12 + hc] + bo[h];
        float a = tanh_f(ga);
        float i = sigm_f(gi);
        float f = sigm_f(gf);
        float o = sigm_f(gO);
        float sprev = FIRST ? 0.f : sbuf[rr * 1024 + h];
        float s = a * i + sprev * f;
        sbuf[rr * 1024 + h] = s;
        float hv = tanh_f(s) * o;
        hnext[rr * 1024 + h] = hv;
        out[((size_t)rr * 512 + t) * 1024 + h] = hv;
    }
}

extern "C" void kernel_launch(void* const* d_in, const int* in_sizes, int n_in,
                              void* d_out, int out_size, void* d_ws, size_t ws_size,
                              hipStream_t stream)
{
    const float* X   = (const float*)d_in[0];
    const float* Wax = (const float*)d_in[1];
    const float* Wix = (const float*)d_in[2];
    const float* Wfx = (const float*)d_in[3];
    const float* Wox = (const float*)d_in[4];
    const float* Wah = (const float*)d_in[5];
    const float* Wih = (const float*)d_in[6];
    const float* Wfh = (const float*)d_in[7];
    const float* Woh = (const float*)d_in[8];
    const float* ba  = (const float*)d_in[9];
    const float* bi  = (const float*)d_in[10];
    const float* bfv = (const float*)d_in[11];
    const float* bo  = (const float*)d_in[12];
    float* out = (float*)d_out;

    const size_t XGH  = (size_t)512 * 32 * 4096 * 2;      // 128 MiB fp16 xg
    const size_t WPK  = (size_t)256 * 16384 * 2;          // 8 MiB bf16 packed Wh
    const size_t H16  = (size_t)32 * 1024 * 2;            // 64 KiB bf16 h
    const size_t BAR  = 4096;
    const size_t HBF  = (size_t)32 * 1024 * 4;            // fallback fp32 h

    char* ws = (char*)d_ws;
    const bool big = ws_size >= XGH + WPK + 2 * H16 + BAR;

    if (big) {
        __half*         xg    = (__half*)ws;
        unsigned short* wpk   = (unsigned short*)(ws + XGH);
        unsigned short* h16A  = (unsigned short*)(ws + XGH + WPK);
        unsigned short* h16B  = (unsigned short*)(ws + XGH + WPK + H16);
        unsigned*       flags = (unsigned*)(ws + XGH + WPK + 2 * H16);
        unsigned*       go    = flags + 256;

        hipMemsetAsync(flags, 0, BAR, stream);
        proj_kernel<<<16384, 256, 0, stream>>>(X, Wax, Wix, Wfx, Wox, xg);

        const unsigned short* xgu = (const unsigned short*)xg;
        void* args[] = {
            (void*)&xgu,
            (void*)&Wah, (void*)&Wih, (void*)&Wfh, (void*)&Woh,
            (void*)&ba, (void*)&bi, (void*)&bfv, (void*)&bo,
            (void*)&wpk, (void*)&h16A, (void*)&h16B,
            (void*)&flags, (void*)&go, (void*)&out
        };
        hipLaunchCooperativeKernel((void*)lstm_persist, dim3(256), dim3(512),
                                   args, 0, stream);
    } else {
        float* h0 = (float*)ws;
        float* h1 = (float*)(ws + HBF);
        float* sb = (float*)(ws + 2 * HBF);
        float* hb[2] = { h0, h1 };
        for (int t = 0; t < 512; ++t) {
            const float* hprev = hb[(t + 1) & 1];
            float* hnext = hb[t & 1];
            if (t == 0)
                step_kernel<true><<<256, 256, 0, stream>>>(hprev, hnext, sb, X,
                    Wah, Wih, Wfh, Woh, Wax, Wix, Wfx, Wox, ba, bi, bfv, bo, out, t);
            else
                step_kernel<false><<<256, 256, 0, stream>>>(hprev, hnext, sb, X,
                    Wah, Wih, Wfh, Woh, Wax, Wix, Wfx, Wox, ba, bi, bfv, bo, out, t);
        }
    }
}

// Round 4
// 2030.154 us; speedup vs baseline: 31.3546x; 1.8582x over previous
//
#include <hip/hip_runtime.h>
#include <hip/hip_fp16.h>

// LSTM: B=32, T=512, D=1024, H=1024.
// Pipeline: (1) W transpose+cvt -> Wt fp16 [4096][1024]  (~15us)
//           (2) proj GEMM xg = X @ Wx via fp16 MFMA       (~0.3ms)
//           (3) persistent cooperative recurrent kernel, fp16 MFMA,
//               flat single-round-trip grid barrier        (~1.7ms)

typedef __attribute__((ext_vector_type(8))) _Float16 f16x8;
typedef __attribute__((ext_vector_type(8))) short    short8;
typedef __attribute__((ext_vector_type(4))) float    f32x4;

__device__ __forceinline__ float sigm_f(float x) { return 1.0f / (1.0f + __expf(-x)); }
__device__ __forceinline__ float tanh_f(float x) { return 1.0f - 2.0f / (__expf(2.0f * x) + 1.0f); }

// system-coherent 16B load: issued WITHOUT wait; caller must s_waitcnt vmcnt(0)
// + sched_barrier(0) before consuming.
__device__ __forceinline__ void ld_sys_b128(short8& d, const void* p) {
    asm volatile("global_load_dwordx4 %0, %1, off sc0 sc1" : "=v"(d) : "v"(p) : "memory");
}
__device__ __forceinline__ void st_sys_u16(void* p, unsigned v) {
    asm volatile("global_store_short %0, %1, off sc0 sc1" :: "v"(p), "v"(v) : "memory");
}

// ---------------- W transpose + fp16 convert ----------------
// Wt[g*1024 + c][k] = W_g[k][c], fp16.  Grid 1024 blocks x 256.
__global__ __launch_bounds__(256)
void wtrans_kernel(const float* __restrict__ Wa, const float* __restrict__ Wi,
                   const float* __restrict__ Wf, const float* __restrict__ Wo,
                   unsigned short* __restrict__ Wt)
{
    __shared__ float Ts[64][65];
    const int bx = blockIdx.x;
    const int g  = bx >> 8;
    const int k0 = ((bx >> 4) & 15) * 64;
    const int c0 = (bx & 15) * 64;
    const float* W = (g == 0) ? Wa : ((g == 1) ? Wi : ((g == 2) ? Wf : Wo));
    const int tid = threadIdx.x;
#pragma unroll
    for (int u = 0; u < 4; ++u) {
        int r  = u * 16 + (tid >> 4);
        int c4 = (tid & 15) * 4;
        float4 v = *reinterpret_cast<const float4*>(W + (size_t)(k0 + r) * 1024 + c0 + c4);
        Ts[r][c4 + 0] = v.x; Ts[r][c4 + 1] = v.y; Ts[r][c4 + 2] = v.z; Ts[r][c4 + 3] = v.w;
    }
    __syncthreads();
#pragma unroll
    for (int u = 0; u < 4; ++u) {
        int col = u * 16 + (tid >> 4);
        int k4  = (tid & 15) * 4;
        unsigned short o[4];
#pragma unroll
        for (int j = 0; j < 4; ++j)
            o[j] = __half_as_ushort(__float2half_rn(Ts[k4 + j][col]));
        *reinterpret_cast<ushort4*>(Wt + ((size_t)g * 1024 + c0 + col) * 1024 + k0 + k4) =
            *reinterpret_cast<ushort4*>(o);
    }
}

// ---------------- Projection GEMM via fp16 MFMA ----------------
// xg[t][b][gcol] = sum_k X[b*512+t][k] * Wt[gcol][k].  M=16384, N=4096, K=1024.
// 128x128 tile, 256 thr / 4 waves, wave = 64x64 (4x4 frags of 16x16), BK=32.
__global__ __launch_bounds__(256)
void proj_mfma(const float* __restrict__ X,
               const _Float16* __restrict__ Wt,
               unsigned short* __restrict__ xg)
{
    __shared__ _Float16 As[128 * 40];   // [row][k] pad-40 halves (80B rows, 16B aligned)
    __shared__ _Float16 Bs[128 * 40];   // [col][k] pad-40

    const int tid  = threadIdx.x;
    const int bn   = blockIdx.x & 31;          // 32 col tiles
    const int bm   = blockIdx.x >> 5;          // 128 row tiles
    const int row0 = bm * 128, col0 = bn * 128;
    const int w    = tid >> 6, lane = tid & 63;
    const int wm   = w >> 1,  wn   = w & 1;
    const int lr   = lane & 15, ko = lane >> 4;

    f32x4 acc[4][4];
#pragma unroll
    for (int mi = 0; mi < 4; ++mi)
#pragma unroll
        for (int ni = 0; ni < 4; ++ni)
            acc[mi][ni] = f32x4{0.f, 0.f, 0.f, 0.f};

    for (int kt = 0; kt < 1024; kt += 32) {
        // stage A: 128x32 fp32 -> fp16
#pragma unroll
        for (int u = 0; u < 4; ++u) {
            int f4 = u * 256 + tid;
            int r  = f4 >> 3, kq = (f4 & 7) * 4;
            float4 v = *reinterpret_cast<const float4*>(X + (size_t)(row0 + r) * 1024 + kt + kq);
            _Float16 h4[4] = {(_Float16)v.x, (_Float16)v.y, (_Float16)v.z, (_Float16)v.w};
            *reinterpret_cast<double*>(&As[r * 40 + kq]) = *reinterpret_cast<double*>(h4);
        }
        // stage B: 128x32 fp16 (already transposed)
#pragma unroll
        for (int u = 0; u < 2; ++u) {
            int i8  = u * 256 + tid;
            int col = i8 >> 2, k8 = (i8 & 3) * 8;
            *reinterpret_cast<float4*>(&Bs[col * 40 + k8]) =
                *reinterpret_cast<const float4*>(Wt + (size_t)(col0 + col) * 1024 + kt + k8);
        }
        __syncthreads();

        f16x8 af[4], bf[4];
#pragma unroll
        for (int mi = 0; mi < 4; ++mi)
            af[mi] = *reinterpret_cast<const f16x8*>(&As[(wm * 64 + mi * 16 + lr) * 40 + ko * 8]);
#pragma unroll
        for (int ni = 0; ni < 4; ++ni)
            bf[ni] = *reinterpret_cast<const f16x8*>(&Bs[(wn * 64 + ni * 16 + lr) * 40 + ko * 8]);
#pragma unroll
        for (int mi = 0; mi < 4; ++mi)
#pragma unroll
            for (int ni = 0; ni < 4; ++ni)
                acc[mi][ni] = __builtin_amdgcn_mfma_f32_16x16x32_f16(af[mi], bf[ni], acc[mi][ni], 0, 0, 0);
        __syncthreads();
    }

    // epilogue: C/D layout col=lane&15, row=(lane>>4)*4+reg (HW-validated)
#pragma unroll
    for (int mi = 0; mi < 4; ++mi)
#pragma unroll
        for (int ni = 0; ni < 4; ++ni)
#pragma unroll
            for (int j = 0; j < 4; ++j) {
                int rt = row0 + wm * 64 + mi * 16 + ko * 4 + j;
                int ct = col0 + wn * 64 + ni * 16 + lr;
                int b = rt >> 9, t = rt & 511;
                xg[((size_t)t * 32 + b) * 4096 + ct] =
                    __half_as_ushort(__float2half_rn(acc[mi][ni][j]));
            }
}

// ---------------- Persistent MFMA recurrent kernel ----------------
// 256 blocks x 512 threads (cooperative). Block owns h-cols [blk*4,+4) = 16 gate-cols.
// Flat single-round-trip grid barrier; xg tile staged during barrier wait.
__global__ __launch_bounds__(512)
void lstm_persist(const unsigned short* __restrict__ xg,   // [512][32][4096] fp16
                  const float* __restrict__ Wah, const float* __restrict__ Wih,
                  const float* __restrict__ Wfh, const float* __restrict__ Woh,
                  const float* __restrict__ ba, const float* __restrict__ bi,
                  const float* __restrict__ bfv, const float* __restrict__ bo,
                  unsigned short* __restrict__ wpk,        // [256][16384] fp16 B-frag order
                  unsigned short* __restrict__ h16A,       // [128][32][8] fp16
                  unsigned short* __restrict__ h16B,
                  unsigned* __restrict__ flags,            // [256] pre-zeroed
                  float* __restrict__ out)                 // [32][512][1024]
{
    __shared__ float pbuf[16 * 64 * 4];
    __shared__ float gbuf[32 * 16];
    __shared__ unsigned short xbuf[32][16];

    const int tid  = threadIdx.x;
    const int blk  = blockIdx.x;
    const int hc0  = blk * 4;
    const int wv   = tid >> 6;
    const int lane = tid & 63;

    // pack Wh slice into B-fragment order (fp16), once
    unsigned short* wb = wpk + (size_t)blk * 16384;
#pragma unroll
    for (int q = 0; q < 4; ++q) {
        int fq    = tid * 4 + q;
        int kiter = fq >> 6;
        int ln    = fq & 63;
        int col   = ln & 15;
        int g     = col >> 2, c = col & 3;
        int kbase = kiter * 32 + (ln >> 4) * 8;
        const float* Wg = (g == 0) ? Wah : ((g == 1) ? Wih : ((g == 2) ? Wfh : Woh));
        unsigned short tmp[8];
#pragma unroll
        for (int e = 0; e < 8; ++e)
            tmp[e] = __half_as_ushort(__float2half_rn(Wg[(size_t)(kbase + e) * 1024 + hc0 + c]));
        *reinterpret_cast<int4*>(wb + (size_t)fq * 8) = *reinterpret_cast<int4*>(tmp);
    }

    float biasr[4][4];
    float sreg = 0.f;
    if (tid < 128) {
        int hc = tid & 3;
        biasr[0][hc] = ba [hc0 + hc];
        biasr[1][hc] = bi [hc0 + hc];
        biasr[2][hc] = bfv[hc0 + hc];
        biasr[3][hc] = bo [hc0 + hc];
    }

    __syncthreads();

    const int koct = lane >> 4;
    const int arow = lane & 15;

    for (int t = 0; t < 512; ++t) {
        if (t > 0) {
            // flat barrier: publish flag, stage xg during wait, poll all 256 flags
            __syncthreads();                               // h stores drained (vmcnt0 pre-barrier)
            if (tid == 0)
                __hip_atomic_store(&flags[blk], (unsigned)t, __ATOMIC_RELAXED, __HIP_MEMORY_SCOPE_AGENT);
            if (tid < 128) {                               // overlap: xg tile for step t
                int r = tid >> 2, g = tid & 3;
                ushort4 v = *reinterpret_cast<const ushort4*>(
                    xg + ((size_t)t * 32 + r) * 4096 + g * 1024 + hc0);
                *reinterpret_cast<ushort4*>(&xbuf[r][g * 4]) = v;
            }
            if (tid < 64) {
                for (;;) {
                    unsigned m0 = __hip_atomic_load(&flags[tid * 4 + 0], __ATOMIC_RELAXED, __HIP_MEMORY_SCOPE_AGENT);
                    unsigned m1 = __hip_atomic_load(&flags[tid * 4 + 1], __ATOMIC_RELAXED, __HIP_MEMORY_SCOPE_AGENT);
                    unsigned m2 = __hip_atomic_load(&flags[tid * 4 + 2], __ATOMIC_RELAXED, __HIP_MEMORY_SCOPE_AGENT);
                    unsigned m3 = __hip_atomic_load(&flags[tid * 4 + 3], __ATOMIC_RELAXED, __HIP_MEMORY_SCOPE_AGENT);
                    unsigned mn = min(min(m0, m1), min(m2, m3));
                    if (__all(mn >= (unsigned)t)) break;
                    __builtin_amdgcn_s_sleep(1);
                }
            }
            __syncthreads();
        } else {
            if (tid < 128) {
                int r = tid >> 2, g = tid & 3;
                ushort4 v = *reinterpret_cast<const ushort4*>(
                    xg + ((size_t)r * 4096) + g * 1024 + hc0);
                *reinterpret_cast<ushort4*>(&xbuf[r][g * 4]) = v;
            }
        }

        const unsigned short* hp = (t & 1) ? h16A : h16B;
        unsigned short*       hn = (t & 1) ? h16B : h16A;

        if (t > 0) {
            short8 a0[4], a1[4], b[4];
#pragma unroll
            for (int ki = 0; ki < 4; ++ki) {
                int kit = wv * 4 + ki;
                int oct = kit * 4 + koct;
                ld_sys_b128(a0[ki], hp + ((size_t)(oct * 32 + arow) * 8));
                ld_sys_b128(a1[ki], hp + ((size_t)(oct * 32 + arow + 16) * 8));
                b[ki] = *reinterpret_cast<const short8*>(wb + ((size_t)(kit * 64 + lane) * 8));
            }
            asm volatile("s_waitcnt vmcnt(0)" ::: "memory");
            __builtin_amdgcn_sched_barrier(0);

            f32x4 acc0 = {0.f, 0.f, 0.f, 0.f};
            f32x4 acc1 = {0.f, 0.f, 0.f, 0.f};
#pragma unroll
            for (int ki = 0; ki < 4; ++ki) {
                acc0 = __builtin_amdgcn_mfma_f32_16x16x32_f16(
                    __builtin_bit_cast(f16x8, a0[ki]), __builtin_bit_cast(f16x8, b[ki]), acc0, 0, 0, 0);
                acc1 = __builtin_amdgcn_mfma_f32_16x16x32_f16(
                    __builtin_bit_cast(f16x8, a1[ki]), __builtin_bit_cast(f16x8, b[ki]), acc1, 0, 0, 0);
            }
            *reinterpret_cast<f32x4*>(&pbuf[((wv * 2 + 0) * 64 + lane) * 4]) = acc0;
            *reinterpret_cast<f32x4*>(&pbuf[((wv * 2 + 1) * 64 + lane) * 4]) = acc1;
        }
        __syncthreads();

        if (t > 0) {
            int m  = tid >> 8;
            int ln = (tid >> 2) & 63;
            int rg = tid & 3;
            float s = 0.f;
#pragma unroll
            for (int w = 0; w < 8; ++w)
                s += pbuf[((w * 2 + m) * 64 + ln) * 4 + rg];
            int row = m * 16 + (ln >> 4) * 4 + rg;
            int col = ln & 15;
            gbuf[row * 16 + col] = s;
        }
        __syncthreads();

        if (tid < 128) {
            const int row = tid >> 2;
            const int hc  = tid & 3;
            float ga = (t > 0 ? gbuf[row * 16 + 0 * 4 + hc] : 0.f) + biasr[0][hc]
                     + __half2float(__ushort_as_half(xbuf[row][0 * 4 + hc]));
            float gi = (t > 0 ? gbuf[row * 16 + 1 * 4 + hc] : 0.f) + biasr[1][hc]
                     + __half2float(__ushort_as_half(xbuf[row][1 * 4 + hc]));
            float gf = (t > 0 ? gbuf[row * 16 + 2 * 4 + hc] : 0.f) + biasr[2][hc]
                     + __half2float(__ushort_as_half(xbuf[row][2 * 4 + hc]));
            float gO = (t > 0 ? gbuf[row * 16 + 3 * 4 + hc] : 0.f) + biasr[3][hc]
                     + __half2float(__ushort_as_half(xbuf[row][3 * 4 + hc]));
            float a  = tanh_f(ga);
            float ii = sigm_f(gi);
            float ff = sigm_f(gf);
            float oo = sigm_f(gO);
            sreg = a * ii + sreg * ff;
            float hv = tanh_f(sreg) * oo;

            out[((size_t)row * 512 + t) * 1024 + hc0 + hc] = hv;
            int colg = hc0 + hc;
            st_sys_u16(hn + ((size_t)((colg >> 3) * 32 + row) * 8 + (colg & 7)),
                       (unsigned)__half_as_ushort(__float2half_rn(hv)));
        }
    }
}

// ---------------- Fallback per-step kernel (round-1 FUSED, fp32) ----------------
template<bool FIRST>
__global__ __launch_bounds__(256)
void step_kernel(const float* __restrict__ hprev, float* __restrict__ hnext,
                 float* __restrict__ sbuf, const float* __restrict__ X,
                 const float* __restrict__ Wah, const float* __restrict__ Wih,
                 const float* __restrict__ Wfh, const float* __restrict__ Woh,
                 const float* __restrict__ Wax, const float* __restrict__ Wix,
                 const float* __restrict__ Wfx, const float* __restrict__ Wox,
                 const float* __restrict__ ba, const float* __restrict__ bi,
                 const float* __restrict__ bfv, const float* __restrict__ bo,
                 float* __restrict__ out, int t)
{
    __shared__ float hs[32 * 1028];
    __shared__ float gs[2][32][16];

    const int tid  = threadIdx.x;
    const int hc0  = blockIdx.x * 4;
    const int kh   = tid >> 7;
    const int gtid = tid & 127;
    const int r    = gtid >> 2;
    const int gate = gtid & 3;
    const int k0   = kh * 512;

    float4 acc = make_float4(0.f, 0.f, 0.f, 0.f);

    if (!FIRST) {
        for (int u = 0; u < 32; u++) {
            int f4 = u * 256 + tid;
            int rr = f4 >> 8;
            int kq = (f4 & 255) << 2;
            *reinterpret_cast<float4*>(&hs[rr * 1028 + kq]) =
                *reinterpret_cast<const float4*>(hprev + rr * 1024 + kq);
        }
        __syncthreads();
        const float* Wg = (gate == 0) ? Wah : ((gate == 1) ? Wih : ((gate == 2) ? Wfh : Woh));
        const float* Wp = Wg + hc0;
#pragma unroll 4
        for (int k = k0; k < k0 + 512; k += 4) {
            float4 hv = *reinterpret_cast<const float4*>(&hs[r * 1028 + k]);
            float4 w0 = *reinterpret_cast<const float4*>(Wp + (size_t)(k + 0) * 1024);
            float4 w1 = *reinterpret_cast<const float4*>(Wp + (size_t)(k + 1) * 1024);
            float4 w2 = *reinterpret_cast<const float4*>(Wp + (size_t)(k + 2) * 1024);
            float4 w3 = *reinterpret_cast<const float4*>(Wp + (size_t)(k + 3) * 1024);
            acc.x += hv.x * w0.x + hv.y * w1.x + hv.z * w2.x + hv.w * w3.x;
            acc.y += hv.x * w0.y + hv.y * w1.y + hv.z * w2.y + hv.w * w3.y;
            acc.z += hv.x * w0.z + hv.y * w1.z + hv.z * w2.z + hv.w * w3.z;
            acc.w += hv.x * w0.w + hv.y * w1.w + hv.z * w2.w + hv.w * w3.w;
        }
    }
    {
        __syncthreads();
        for (int u = 0; u < 32; u++) {
            int f4 = u * 256 + tid;
            int rr = f4 >> 8;
            int kq = (f4 & 255) << 2;
            *reinterpret_cast<float4*>(&hs[rr * 1028 + kq]) =
                *reinterpret_cast<const float4*>(X + ((size_t)rr * 512 + t) * 1024 + kq);
        }
        __syncthreads();
        const float* Wg = (gate == 0) ? Wax : ((gate == 1) ? Wix : ((gate == 2) ? Wfx : Wox));
        const float* Wp = Wg + hc0;
#pragma unroll 4
        for (int k = k0; k < k0 + 512; k += 4) {
            float4 hv = *reinterpret_cast<const float4*>(&hs[r * 1028 + k]);
            float4 w0 = *reinterpret_cast<const float4*>(Wp + (size_t)(k + 0) * 1024);
            float4 w1 = *reinterpret_cast<const float4*>(Wp + (size_t)(k + 1) * 1024);
            float4 w2 = *reinterpret_cast<const float4*>(Wp + (size_t)(k + 2) * 1024);
            float4 w3 = *reinterpret_cast<const float4*>(Wp + (size_t)(k + 3) * 1024);
            acc.x += hv.x * w0.x + hv.y * w1.x + hv.z * w2.x + hv.w * w3.x;
            acc.y += hv.x * w0.y + hv.y * w1.y + hv.z * w2.y + hv.w * w3.y;
            acc.z += hv.x * w0.z + hv.y * w1.z + hv.z * w2.z + hv.w * w3.z;
            acc.w += hv.x * w0.w + hv.y * w1.w + hv.z * w2.w + hv.w * w3.w;
        }
    }

    *reinterpret_cast<float4*>(&gs[kh][r][gate * 4]) = acc;
    __syncthreads();

    if (tid < 128) {
        const int rr = tid >> 2;
        const int hc = tid & 3;
        const int h  = hc0 + hc;
        float ga = gs[0][rr][0 + hc]  + gs[1][rr][0 + hc]  + ba[h];
        float gi = gs[0][rr][4 + hc]  + gs[1][rr][4 + hc]  + bi[h];
        float gf = gs[0][rr][8 + hc]  + gs[1][rr][8 + hc]  + bfv[h];
        float gO = gs[0][rr][12 + hc] + gs[1][rr][12 + hc] + bo[h];
        float a = tanh_f(ga);
        float i = sigm_f(gi);
        float f = sigm_f(gf);
        float o = sigm_f(gO);
        float sprev = FIRST ? 0.f : sbuf[rr * 1024 + h];
        float s = a * i + sprev * f;
        sbuf[rr * 1024 + h] = s;
        float hv = tanh_f(s) * o;
        hnext[rr * 1024 + h] = hv;
        out[((size_t)rr * 512 + t) * 1024 + h] = hv;
    }
}

extern "C" void kernel_launch(void* const* d_in, const int* in_sizes, int n_in,
                              void* d_out, int out_size, void* d_ws, size_t ws_size,
                              hipStream_t stream)
{
    const float* X   = (const float*)d_in[0];
    const float* Wax = (const float*)d_in[1];
    const float* Wix = (const float*)d_in[2];
    const float* Wfx = (const float*)d_in[3];
    const float* Wox = (const float*)d_in[4];
    const float* Wah = (const float*)d_in[5];
    const float* Wih = (const float*)d_in[6];
    const float* Wfh = (const float*)d_in[7];
    const float* Woh = (const float*)d_in[8];
    const float* ba  = (const float*)d_in[9];
    const float* bi  = (const float*)d_in[10];
    const float* bfv = (const float*)d_in[11];
    const float* bo  = (const float*)d_in[12];
    float* out = (float*)d_out;

    const size_t XGH  = (size_t)512 * 32 * 4096 * 2;      // 128 MiB fp16 xg
    const size_t WPK  = (size_t)256 * 16384 * 2;          // 8 MiB fp16 packed Wh
    const size_t WTX  = (size_t)4096 * 1024 * 2;          // 8 MiB fp16 Wt
    const size_t H16  = (size_t)32 * 1024 * 2;            // 64 KiB fp16 h
    const size_t BAR  = 4096;
    const size_t HBF  = (size_t)32 * 1024 * 4;

    char* ws = (char*)d_ws;
    const bool big = ws_size >= XGH + WPK + WTX + 2 * H16 + BAR;

    if (big) {
        unsigned short* xg    = (unsigned short*)ws;
        unsigned short* wpk   = (unsigned short*)(ws + XGH);
        unsigned short* Wt    = (unsigned short*)(ws + XGH + WPK);
        unsigned short* h16A  = (unsigned short*)(ws + XGH + WPK + WTX);
        unsigned short* h16B  = (unsigned short*)(ws + XGH + WPK + WTX + H16);
        unsigned*       flags = (unsigned*)(ws + XGH + WPK + WTX + 2 * H16);

        hipMemsetAsync(flags, 0, BAR, stream);
        wtrans_kernel<<<1024, 256, 0, stream>>>(Wax, Wix, Wfx, Wox, Wt);
        proj_mfma<<<4096, 256, 0, stream>>>(X, (const _Float16*)Wt, xg);

        const unsigned short* xgu = xg;
        void* args[] = {
            (void*)&xgu,
            (void*)&Wah, (void*)&Wih, (void*)&Wfh, (void*)&Woh,
            (void*)&ba, (void*)&bi, (void*)&bfv, (void*)&bo,
            (void*)&wpk, (void*)&h16A, (void*)&h16B,
            (void*)&flags, (void*)&out
        };
        hipLaunchCooperativeKernel((void*)lstm_persist, dim3(256), dim3(512),
                                   args, 0, stream);
    } else {
        float* h0 = (float*)ws;
        float* h1 = (float*)(ws + HBF);
        float* sb = (float*)(ws + 2 * HBF);
        float* hb[2] = { h0, h1 };
        for (int t = 0; t < 512; ++t) {
            const float* hprev = hb[(t + 1) & 1];
            float* hnext = hb[t & 1];
            if (t == 0)
                step_kernel<true><<<256, 256, 0, stream>>>(hprev, hnext, sb, X,
                    Wah, Wih, Wfh, Woh, Wax, Wix, Wfx, Wox, ba, bi, bfv, bo, out, t);
            else
                step_kernel<false><<<256, 256, 0, stream>>>(hprev, hnext, sb, X,
                    Wah, Wih, Wfh, Woh, Wax, Wix, Wfx, Wox, ba, bi, bfv, bo, out, t);
        }
    }
}